// Round 1
// baseline (1301.691 us; speedup 1.0000x reference)
//
#include <hip/hip_runtime.h>
#include <hip/hip_bf16.h>
#include <stdint.h>

#define THREADS 256

static inline int imin(int a, int b) { return a < b ? a : b; }

// ---------------- edge dtype detection (int32 vs int64) ----------------
// int64 layout: odd 32-bit words are high words == 0 (values in [0,1e5)).
// int32 layout: odd words are random node ids, ~never all zero.
__global__ void k_detect(const int* __restrict__ raw, int* __restrict__ flag) {
    __shared__ int found;
    if (threadIdx.x == 0) found = 0;
    __syncthreads();
    if (raw[2 * threadIdx.x + 1] != 0) atomicOr(&found, 1);
    __syncthreads();
    if (threadIdx.x == 0) *flag = found ? 0 : 1;  // 1 => int64
}

__global__ void k_cvt_edges(const int* __restrict__ raw, int* __restrict__ src,
                            int* __restrict__ dst, int E, const int* __restrict__ flag) {
    const bool is64 = (*flag != 0);
    int i = blockIdx.x * blockDim.x + threadIdx.x;
    const int stride = gridDim.x * blockDim.x;
    for (; i < E; i += stride) {
        if (is64) { src[i] = raw[2 * i];  dst[i] = raw[2 * E + 2 * i]; }
        else      { src[i] = raw[i];      dst[i] = raw[E + i]; }
    }
}

// ---------------- degree histogram / dinv ----------------
__global__ void k_hist(const int* __restrict__ dst, int* __restrict__ deg, int E) {
    int i = blockIdx.x * blockDim.x + threadIdx.x;
    const int stride = gridDim.x * blockDim.x;
    for (; i < E; i += stride) atomicAdd(&deg[dst[i]], 1);
}

__global__ void k_dinv(const int* __restrict__ deg, float* __restrict__ dinv, int N) {
    int i = blockIdx.x * blockDim.x + threadIdx.x;
    const int stride = gridDim.x * blockDim.x;
    for (; i < N; i += stride) dinv[i] = rsqrtf((float)deg[i] + 1.0f);
}

// ---------------- exclusive scan of deg -> rowptr (3 kernels) ----------------
__global__ void k_chunk_sums(const int* __restrict__ deg, int* __restrict__ chunkSum, int N) {
    __shared__ int sm[THREADS];
    const int base = blockIdx.x * 2048 + threadIdx.x * 8;
    int s = 0;
#pragma unroll
    for (int i = 0; i < 8; ++i) { int idx = base + i; if (idx < N) s += deg[idx]; }
    sm[threadIdx.x] = s;
    __syncthreads();
    for (int off = THREADS / 2; off > 0; off >>= 1) {
        if (threadIdx.x < off) sm[threadIdx.x] += sm[threadIdx.x + off];
        __syncthreads();
    }
    if (threadIdx.x == 0) chunkSum[blockIdx.x] = sm[0];
}

__global__ void k_scan_offsets(const int* __restrict__ chunkSum, int* __restrict__ chunkOff,
                               int nChunks, int* __restrict__ rowptr, int N) {
    if (blockIdx.x == 0 && threadIdx.x == 0) {
        int run = 0;
        for (int i = 0; i < nChunks; ++i) { chunkOff[i] = run; run += chunkSum[i]; }
        rowptr[N] = run;
    }
}

__global__ void k_scan_write(const int* __restrict__ deg, const int* __restrict__ chunkOff,
                             int* __restrict__ rowptr, int N) {
    __shared__ int sm[THREADS];
    const int tid = threadIdx.x;
    const int base = blockIdx.x * 2048 + tid * 8;
    int v[8]; int s = 0;
#pragma unroll
    for (int i = 0; i < 8; ++i) { int idx = base + i; v[i] = (idx < N) ? deg[idx] : 0; s += v[i]; }
    const int mysum = s;
    sm[tid] = s;
    __syncthreads();
    for (int off = 1; off < THREADS; off <<= 1) {
        int t = (tid >= off) ? sm[tid - off] : 0;
        __syncthreads();
        sm[tid] += t;
        __syncthreads();
    }
    int run = chunkOff[blockIdx.x] + sm[tid] - mysum;  // exclusive prefix
#pragma unroll
    for (int i = 0; i < 8; ++i) {
        int idx = base + i;
        if (idx < N) { rowptr[idx] = run; run += v[i]; }
    }
}

// ---------------- CSR fill ----------------
__global__ void k_cursor(const int* __restrict__ rowptr, int* __restrict__ cursor, int N) {
    int i = blockIdx.x * blockDim.x + threadIdx.x;
    const int stride = gridDim.x * blockDim.x;
    for (; i < N; i += stride) cursor[i] = rowptr[i];
}

__global__ void k_fill(const int* __restrict__ src, const int* __restrict__ dst,
                       const float* __restrict__ dinv, int* __restrict__ cursor,
                       int* __restrict__ csr_src, float* __restrict__ csr_norm, int E) {
    int i = blockIdx.x * blockDim.x + threadIdx.x;
    const int stride = gridDim.x * blockDim.x;
    for (; i < E; i += stride) {
        const int s = src[i], d = dst[i];
        const int p = atomicAdd(&cursor[d], 1);
        csr_src[p] = s;
        csr_norm[p] = dinv[s] * dinv[d];
    }
}

// ---------------- W2n = -(W @ Wres), cvec = b - bres ----------------
__global__ void k_w2(const float* __restrict__ W, const float* __restrict__ Wres,
                     const float* __restrict__ b, const float* __restrict__ bres,
                     float* __restrict__ W2n, float* __restrict__ cvec) {
    const int gid = blockIdx.x * blockDim.x + threadIdx.x;
    if (gid < 128 * 128) {
        const int i = gid >> 7, j = gid & 127;
        float s = 0.f;
#pragma unroll 8
        for (int k = 0; k < 128; ++k) s += W[i * 128 + k] * Wres[k * 128 + j];
        W2n[gid] = -s;
    }
    if (gid < 128) cvec[gid] = b[gid] - bres[gid];
}

// ---------------- X0 = tanh(x) ----------------
__global__ void k_tanh0(const float* __restrict__ x, float* __restrict__ X, long long n4) {
    long long i = blockIdx.x * (long long)blockDim.x + threadIdx.x;
    const long long stride = gridDim.x * (long long)blockDim.x;
    for (; i < n4; i += stride) {
        float4 v = ((const float4*)x)[i];
        v.x = tanhf(v.x); v.y = tanhf(v.y); v.z = tanhf(v.z); v.w = tanhf(v.w);
        ((float4*)X)[i] = v;
    }
}

// ---------------- P = A_hat @ X  (one wave per node, float2 per lane) ----------------
__global__ void k_agg(const float* __restrict__ X, const int* __restrict__ rowptr,
                      const int* __restrict__ csr_src, const float* __restrict__ csr_norm,
                      const float* __restrict__ dinv, float* __restrict__ P, int N) {
    const int wid = threadIdx.x >> 6;
    const int lane = threadIdx.x & 63;
    const int node = blockIdx.x * 4 + wid;
    if (node >= N) return;
    const int j0 = lane * 2;
    const float dn = dinv[node];
    const float2 xv = *(const float2*)&X[(size_t)node * 128 + j0];
    float a0 = dn * dn * xv.x, a1 = dn * dn * xv.y;
    const int e0 = rowptr[node], e1 = rowptr[node + 1];
    for (int e = e0; e < e1; ++e) {
        const int s = csr_src[e];
        const float w = csr_norm[e];
        const float2 sv = *(const float2*)&X[(size_t)s * 128 + j0];
        a0 = fmaf(w, sv.x, a0);
        a1 = fmaf(w, sv.y, a1);
    }
    *(float2*)&P[(size_t)node * 128 + j0] = make_float2(a0, a1);
}

// ---------------- Xout = tanh(P@W + X@W2n + cvec), in-place safe (row-local) ----
__global__ __launch_bounds__(256)
void k_gemm_tanh(const float* __restrict__ Pm, const float* __restrict__ Xm,
                 const float* __restrict__ W, const float* __restrict__ W2n,
                 const float* __restrict__ cvec, float* __restrict__ Xout, int M) {
    __shared__ float As[8][64];
    __shared__ float Bs[8][128];
    const int tid = threadIdx.x;
    const int brow = blockIdx.x * 64;
    const int ty = tid >> 4;          // 0..15 -> rows ty*4..+3
    const int tx = tid & 15;          // 0..15 -> cols tx*8..+7
    const int arow = tid >> 2;        // 0..63
    const int akc  = (tid & 3) * 2;   // 0,2,4,6
    const int bkr  = tid >> 5;        // 0..7
    const int bcol = (tid & 31) * 4;  // 0..124

    float acc[4][8];
#pragma unroll
    for (int i = 0; i < 4; ++i)
#pragma unroll
        for (int j = 0; j < 8; ++j) acc[i][j] = 0.f;

    const int gr = brow + arow;
    const bool aok = gr < M;

#pragma unroll 1
    for (int phase = 0; phase < 2; ++phase) {
        const float* __restrict__ A = phase ? Xm : Pm;
        const float* __restrict__ B = phase ? W2n : W;
#pragma unroll 1
        for (int ks = 0; ks < 16; ++ks) {
            const int kb = ks * 8;
            float2 av = make_float2(0.f, 0.f);
            if (aok) av = *(const float2*)&A[(size_t)gr * 128 + kb + akc];
            const float4 bv = *(const float4*)&B[(kb + bkr) * 128 + bcol];
            __syncthreads();
            As[akc][arow] = av.x;
            As[akc + 1][arow] = av.y;
            *(float4*)&Bs[bkr][bcol] = bv;
            __syncthreads();
#pragma unroll
            for (int kk = 0; kk < 8; ++kk) {
                const float4 a = *(const float4*)&As[kk][ty * 4];
                const float4 b0 = *(const float4*)&Bs[kk][tx * 8];
                const float4 b1 = *(const float4*)&Bs[kk][tx * 8 + 4];
                const float aa[4] = {a.x, a.y, a.z, a.w};
                const float bb[8] = {b0.x, b0.y, b0.z, b0.w, b1.x, b1.y, b1.z, b1.w};
#pragma unroll
                for (int i = 0; i < 4; ++i)
#pragma unroll
                    for (int j = 0; j < 8; ++j) acc[i][j] = fmaf(aa[i], bb[j], acc[i][j]);
            }
        }
    }

#pragma unroll
    for (int i = 0; i < 4; ++i) {
        const int r = brow + ty * 4 + i;
        if (r < M) {
            float o[8];
#pragma unroll
            for (int j = 0; j < 8; ++j) o[j] = tanhf(acc[i][j] + cvec[tx * 8 + j]);
            *(float4*)&Xout[(size_t)r * 128 + tx * 8]     = make_float4(o[0], o[1], o[2], o[3]);
            *(float4*)&Xout[(size_t)r * 128 + tx * 8 + 4] = make_float4(o[4], o[5], o[6], o[7]);
        }
    }
}

extern "C" void kernel_launch(void* const* d_in, const int* in_sizes, int n_in,
                              void* d_out, int out_size, void* d_ws, size_t ws_size,
                              hipStream_t stream) {
    const float* x    = (const float*)d_in[0];
    const int*   ei   = (const int*)d_in[1];
    const float* W    = (const float*)d_in[2];
    const float* b    = (const float*)d_in[3];
    const float* Wres = (const float*)d_in[4];
    const float* bres = (const float*)d_in[5];
    const int N = in_sizes[0] / 128;
    const int E = in_sizes[1] / 2;
    float* X = (float*)d_out;  // X state lives in d_out

    uint8_t* base = (uint8_t*)d_ws;
    size_t off = 0;
    auto carve = [&](size_t bytes) -> void* {
        void* p = base + off;
        off += (bytes + 255) & ~(size_t)255;
        return p;
    };
    float* P        = (float*)carve((size_t)N * 128 * sizeof(float));
    int*   srcA     = (int*)carve((size_t)E * sizeof(int));
    int*   dstA     = (int*)carve((size_t)E * sizeof(int));
    int*   csr_src  = (int*)carve((size_t)E * sizeof(int));
    float* csr_norm = (float*)carve((size_t)E * sizeof(float));
    int*   deg      = (int*)carve((size_t)N * sizeof(int));
    int*   rowptr   = (int*)carve(((size_t)N + 1) * sizeof(int));
    int*   cursor   = (int*)carve((size_t)N * sizeof(int));
    float* dinv     = (float*)carve((size_t)N * sizeof(float));
    float* W2n      = (float*)carve(128 * 128 * sizeof(float));
    float* cvec     = (float*)carve(128 * sizeof(float));
    int*   chunkSum = (int*)carve(4096);
    int*   chunkOff = (int*)carve(4096);
    int*   flag     = (int*)carve(256);

    hipMemsetAsync(deg, 0, (size_t)N * sizeof(int), stream);

    const int egrid = imin((E + THREADS - 1) / THREADS, 2048);
    const int ngrid = imin((N + THREADS - 1) / THREADS, 2048);
    const int nChunks = (N + 2047) / 2048;

    k_detect<<<1, 256, 0, stream>>>(ei, flag);
    k_cvt_edges<<<egrid, THREADS, 0, stream>>>(ei, srcA, dstA, E, flag);
    k_hist<<<egrid, THREADS, 0, stream>>>(dstA, deg, E);
    k_dinv<<<ngrid, THREADS, 0, stream>>>(deg, dinv, N);
    k_chunk_sums<<<nChunks, THREADS, 0, stream>>>(deg, chunkSum, N);
    k_scan_offsets<<<1, 64, 0, stream>>>(chunkSum, chunkOff, nChunks, rowptr, N);
    k_scan_write<<<nChunks, THREADS, 0, stream>>>(deg, chunkOff, rowptr, N);
    k_cursor<<<ngrid, THREADS, 0, stream>>>(rowptr, cursor, N);
    k_fill<<<egrid, THREADS, 0, stream>>>(srcA, dstA, dinv, cursor, csr_src, csr_norm, E);
    k_w2<<<64, THREADS, 0, stream>>>(W, Wres, b, bres, W2n, cvec);

    const long long n4 = (long long)N * 32;
    const int tgrid = imin((int)((n4 + THREADS - 1) / THREADS), 2048);
    k_tanh0<<<tgrid, THREADS, 0, stream>>>(x, X, n4);

    for (int l = 0; l < 4; ++l) {
        k_agg<<<(N + 3) / 4, THREADS, 0, stream>>>(X, rowptr, csr_src, csr_norm, dinv, P, N);
        k_gemm_tanh<<<(N + 63) / 64, THREADS, 0, stream>>>(P, X, W, W2n, cvec, X, N);
    }
}

// Round 2
// 843.541 us; speedup vs baseline: 1.5431x; 1.5431x over previous
//
#include <hip/hip_runtime.h>
#include <hip/hip_bf16.h>
#include <stdint.h>

#define THREADS 256
typedef unsigned short u16;
typedef unsigned int u32;
using frag_ab = __attribute__((ext_vector_type(8))) short;   // 8 bf16 (4 VGPR)
using f32x4  = __attribute__((ext_vector_type(4))) float;    // 4 fp32 acc

static inline int imin(int a, int b) { return a < b ? a : b; }

static __device__ inline u16 f2b(float f) {               // f32 -> bf16 RNE
    u32 u = __builtin_bit_cast(u32, f);
    return (u16)((u + 0x7FFFu + ((u >> 16) & 1u)) >> 16);
}
static __device__ inline float b2f_lo(u32 v) { return __builtin_bit_cast(float, v << 16); }
static __device__ inline float b2f_hi(u32 v) { return __builtin_bit_cast(float, v & 0xFFFF0000u); }

// ---------------- edge dtype detection (int32 vs int64) ----------------
__global__ void k_detect(const int* __restrict__ raw, int* __restrict__ flag) {
    __shared__ int found;
    if (threadIdx.x == 0) found = 0;
    __syncthreads();
    if (raw[2 * threadIdx.x + 1] != 0) atomicOr(&found, 1);
    __syncthreads();
    if (threadIdx.x == 0) *flag = found ? 0 : 1;  // 1 => int64
}

__global__ void k_cvt_edges(const int* __restrict__ raw, int* __restrict__ src,
                            int* __restrict__ dst, int E, const int* __restrict__ flag) {
    const bool is64 = (*flag != 0);
    int i = blockIdx.x * blockDim.x + threadIdx.x;
    const int stride = gridDim.x * blockDim.x;
    for (; i < E; i += stride) {
        if (is64) { src[i] = raw[2 * i];  dst[i] = raw[2 * E + 2 * i]; }
        else      { src[i] = raw[i];      dst[i] = raw[E + i]; }
    }
}

// ---------------- degree histogram / dinv ----------------
__global__ void k_hist(const int* __restrict__ dst, int* __restrict__ deg, int E) {
    int i = blockIdx.x * blockDim.x + threadIdx.x;
    const int stride = gridDim.x * blockDim.x;
    for (; i < E; i += stride) atomicAdd(&deg[dst[i]], 1);
}

__global__ void k_dinv(const int* __restrict__ deg, float* __restrict__ dinv, int N) {
    int i = blockIdx.x * blockDim.x + threadIdx.x;
    const int stride = gridDim.x * blockDim.x;
    for (; i < N; i += stride) dinv[i] = rsqrtf((float)deg[i] + 1.0f);
}

// ---------------- exclusive scan of deg -> rowptr ----------------
__global__ void k_chunk_sums(const int* __restrict__ deg, int* __restrict__ chunkSum, int N) {
    __shared__ int sm[THREADS];
    const int base = blockIdx.x * 2048 + threadIdx.x * 8;
    int s = 0;
#pragma unroll
    for (int i = 0; i < 8; ++i) { int idx = base + i; if (idx < N) s += deg[idx]; }
    sm[threadIdx.x] = s;
    __syncthreads();
    for (int off = THREADS / 2; off > 0; off >>= 1) {
        if (threadIdx.x < off) sm[threadIdx.x] += sm[threadIdx.x + off];
        __syncthreads();
    }
    if (threadIdx.x == 0) chunkSum[blockIdx.x] = sm[0];
}

__global__ void k_scan_offsets(const int* __restrict__ chunkSum, int* __restrict__ chunkOff,
                               int nChunks, int* __restrict__ rowptr, int N) {
    if (blockIdx.x == 0 && threadIdx.x == 0) {
        int run = 0;
        for (int i = 0; i < nChunks; ++i) { chunkOff[i] = run; run += chunkSum[i]; }
        rowptr[N] = run;
    }
}

__global__ void k_scan_write(const int* __restrict__ deg, const int* __restrict__ chunkOff,
                             int* __restrict__ rowptr, int N) {
    __shared__ int sm[THREADS];
    const int tid = threadIdx.x;
    const int base = blockIdx.x * 2048 + tid * 8;
    int v[8]; int s = 0;
#pragma unroll
    for (int i = 0; i < 8; ++i) { int idx = base + i; v[i] = (idx < N) ? deg[idx] : 0; s += v[i]; }
    const int mysum = s;
    sm[tid] = s;
    __syncthreads();
    for (int off = 1; off < THREADS; off <<= 1) {
        int t = (tid >= off) ? sm[tid - off] : 0;
        __syncthreads();
        sm[tid] += t;
        __syncthreads();
    }
    int run = chunkOff[blockIdx.x] + sm[tid] - mysum;
#pragma unroll
    for (int i = 0; i < 8; ++i) {
        int idx = base + i;
        if (idx < N) { rowptr[idx] = run; run += v[i]; }
    }
}

// ---------------- CSR fill ----------------
__global__ void k_cursor(const int* __restrict__ rowptr, int* __restrict__ cursor, int N) {
    int i = blockIdx.x * blockDim.x + threadIdx.x;
    const int stride = gridDim.x * blockDim.x;
    for (; i < N; i += stride) cursor[i] = rowptr[i];
}

__global__ void k_fill(const int* __restrict__ src, const int* __restrict__ dst,
                       const float* __restrict__ dinv, int* __restrict__ cursor,
                       int* __restrict__ csr_src, float* __restrict__ csr_norm, int E) {
    int i = blockIdx.x * blockDim.x + threadIdx.x;
    const int stride = gridDim.x * blockDim.x;
    for (; i < E; i += stride) {
        const int s = src[i], d = dst[i];
        const int p = atomicAdd(&cursor[d], 1);
        csr_src[p] = s;
        csr_norm[p] = dinv[s] * dinv[d];
    }
}

// ---- Bt[n][k] (128 x 256 bf16, col-major concat [W ; -(W@Wres)]) + cvec = b-bres ----
__global__ void k_w2(const float* __restrict__ W, const float* __restrict__ Wres,
                     const float* __restrict__ b, const float* __restrict__ bres,
                     u16* __restrict__ Bt, float* __restrict__ cvec) {
    const int gid = blockIdx.x * blockDim.x + threadIdx.x;
    if (gid < 128 * 128) {
        const int i = gid >> 7, n = gid & 127;   // i = K row of W2, n = output col
        float s = 0.f;
#pragma unroll 8
        for (int k = 0; k < 128; ++k) s += W[i * 128 + k] * Wres[k * 128 + n];
        Bt[n * 256 + 128 + i] = f2b(-s);          // residual half: -(W@Wres)[i][n]
        Bt[n * 256 + i]       = f2b(W[i * 128 + n]);  // conv half: W[i][n]
    }
    if (gid < 128) cvec[gid] = b[gid] - bres[gid];
}

// ---------------- Xh0 = bf16(tanh(x)) ----------------
__global__ void k_tanh0(const float* __restrict__ x, u16* __restrict__ Xh, long long n4) {
    long long i = blockIdx.x * (long long)blockDim.x + threadIdx.x;
    const long long stride = gridDim.x * (long long)blockDim.x;
    for (; i < n4; i += stride) {
        float4 v = ((const float4*)x)[i];
        u32 lo = f2b(tanhf(v.x)) | ((u32)f2b(tanhf(v.y)) << 16);
        u32 hi = f2b(tanhf(v.z)) | ((u32)f2b(tanhf(v.w)) << 16);
        ((uint2*)Xh)[i] = make_uint2(lo, hi);
    }
}

// ------- Ph = bf16(A_hat @ Xh)  (one wave per node, bf16x2 per lane, fp32 accum) -------
__global__ void k_agg(const u16* __restrict__ Xh, const int* __restrict__ rowptr,
                      const int* __restrict__ csr_src, const float* __restrict__ csr_norm,
                      const float* __restrict__ dinv, u16* __restrict__ Ph, int N) {
    const int wid = threadIdx.x >> 6;
    const int lane = threadIdx.x & 63;
    const int node = blockIdx.x * 4 + wid;
    if (node >= N) return;
    const int j0 = lane * 2;
    const float dn = dinv[node];
    const u32 xv = *(const u32*)&Xh[(size_t)node * 128 + j0];
    float a0 = dn * dn * b2f_lo(xv), a1 = dn * dn * b2f_hi(xv);
    const int e0 = rowptr[node], e1 = rowptr[node + 1];
    int e = e0;
    for (; e + 1 < e1; e += 2) {
        const int s0 = csr_src[e], s1 = csr_src[e + 1];
        const float w0 = csr_norm[e], w1 = csr_norm[e + 1];
        const u32 v0 = *(const u32*)&Xh[(size_t)s0 * 128 + j0];
        const u32 v1 = *(const u32*)&Xh[(size_t)s1 * 128 + j0];
        a0 = fmaf(w0, b2f_lo(v0), a0); a1 = fmaf(w0, b2f_hi(v0), a1);
        a0 = fmaf(w1, b2f_lo(v1), a0); a1 = fmaf(w1, b2f_hi(v1), a1);
    }
    if (e < e1) {
        const int s0 = csr_src[e];
        const float w0 = csr_norm[e];
        const u32 v0 = *(const u32*)&Xh[(size_t)s0 * 128 + j0];
        a0 = fmaf(w0, b2f_lo(v0), a0); a1 = fmaf(w0, b2f_hi(v0), a1);
    }
    *(u32*)&Ph[(size_t)node * 128 + j0] = (u32)f2b(a0) | ((u32)f2b(a1) << 16);
}

// -------- Xh = bf16(tanh([Ph|Xh] @ Bt^T + cvec)); optionally fp32 out (last layer) ----
// 256 thr = 4 waves; block tile 128 rows x 128 cols; wave tile 32x128.
// mfma_f32_16x16x32_bf16: A lane: row=l&15, k=8*(l>>4)+j ; B lane: col=l&15, same k ;
// D lane: col=l&15, row=4*(l>>4)+reg  [guide §3, m89-verified]
__global__ __launch_bounds__(256)
void k_gemm_mfma(const u16* __restrict__ Ph, const u16* __restrict__ Xh,
                 const u16* __restrict__ Bt, const float* __restrict__ cvec,
                 float* __restrict__ Xout, u16* __restrict__ XhOut, int M, int writeF32) {
    const int wid = threadIdx.x >> 6;
    const int lane = threadIdx.x & 63;
    const int rowbase = blockIdx.x * 128 + wid * 32;
    const int rl = lane & 15;
    const int kg = (lane >> 4) * 8;

    f32x4 acc[2][8];
#pragma unroll
    for (int i = 0; i < 2; ++i)
#pragma unroll
        for (int j = 0; j < 8; ++j) acc[i][j] = (f32x4){0.f, 0.f, 0.f, 0.f};

    const int r0 = rowbase + rl;
    const size_t ar0 = (size_t)((r0      < M) ? r0      : M - 1);
    const size_t ar1 = (size_t)((r0 + 16 < M) ? r0 + 16 : M - 1);

#pragma unroll 1
    for (int ks = 0; ks < 8; ++ks) {
        const u16* Abase = (ks < 4) ? Ph : Xh;
        const int kk = (ks & 3) * 32 + kg;       // k within the 128-wide A half
        const frag_ab a0 = *(const frag_ab*)&Abase[ar0 * 128 + kk];
        const frag_ab a1 = *(const frag_ab*)&Abase[ar1 * 128 + kk];
        const int kb = ks * 32 + kg;             // k within the 256-wide Bt row
#pragma unroll
        for (int nf = 0; nf < 8; ++nf) {
            const frag_ab bv = *(const frag_ab*)&Bt[(size_t)(nf * 16 + rl) * 256 + kb];
            acc[0][nf] = __builtin_amdgcn_mfma_f32_16x16x32_bf16(a0, bv, acc[0][nf], 0, 0, 0);
            acc[1][nf] = __builtin_amdgcn_mfma_f32_16x16x32_bf16(a1, bv, acc[1][nf], 0, 0, 0);
        }
    }

    const int rq = (lane >> 4) * 4;
#pragma unroll
    for (int mf = 0; mf < 2; ++mf) {
#pragma unroll
        for (int nf = 0; nf < 8; ++nf) {
            const int c = nf * 16 + rl;
            const float cv = cvec[c];
#pragma unroll
            for (int reg = 0; reg < 4; ++reg) {
                const int r = rowbase + mf * 16 + rq + reg;
                if (r < M) {
                    const float v = tanhf(acc[mf][nf][reg] + cv);
                    XhOut[(size_t)r * 128 + c] = f2b(v);
                    if (writeF32) Xout[(size_t)r * 128 + c] = v;
                }
            }
        }
    }
}

extern "C" void kernel_launch(void* const* d_in, const int* in_sizes, int n_in,
                              void* d_out, int out_size, void* d_ws, size_t ws_size,
                              hipStream_t stream) {
    const float* x    = (const float*)d_in[0];
    const int*   ei   = (const int*)d_in[1];
    const float* W    = (const float*)d_in[2];
    const float* b    = (const float*)d_in[3];
    const float* Wres = (const float*)d_in[4];
    const float* bres = (const float*)d_in[5];
    const int N = in_sizes[0] / 128;
    const int E = in_sizes[1] / 2;
    float* X = (float*)d_out;

    uint8_t* base = (uint8_t*)d_ws;
    size_t off = 0;
    auto carve = [&](size_t bytes) -> void* {
        void* p = base + off;
        off += (bytes + 255) & ~(size_t)255;
        return p;
    };
    u16*   Xh       = (u16*)carve((size_t)N * 128 * sizeof(u16));
    u16*   Ph       = (u16*)carve((size_t)N * 128 * sizeof(u16));
    int*   srcA     = (int*)carve((size_t)E * sizeof(int));
    int*   dstA     = (int*)carve((size_t)E * sizeof(int));
    int*   csr_src  = (int*)carve((size_t)E * sizeof(int));
    float* csr_norm = (float*)carve((size_t)E * sizeof(float));
    int*   deg      = (int*)carve((size_t)N * sizeof(int));
    int*   rowptr   = (int*)carve(((size_t)N + 1) * sizeof(int));
    int*   cursor   = (int*)carve((size_t)N * sizeof(int));
    float* dinv     = (float*)carve((size_t)N * sizeof(float));
    u16*   Bt       = (u16*)carve(128 * 256 * sizeof(u16));
    float* cvec     = (float*)carve(128 * sizeof(float));
    int*   chunkSum = (int*)carve(4096);
    int*   chunkOff = (int*)carve(4096);
    int*   flag     = (int*)carve(256);

    hipMemsetAsync(deg, 0, (size_t)N * sizeof(int), stream);

    const int egrid = imin((E + THREADS - 1) / THREADS, 2048);
    const int ngrid = imin((N + THREADS - 1) / THREADS, 2048);
    const int nChunks = (N + 2047) / 2048;

    k_detect<<<1, 256, 0, stream>>>(ei, flag);
    k_cvt_edges<<<egrid, THREADS, 0, stream>>>(ei, srcA, dstA, E, flag);
    k_hist<<<egrid, THREADS, 0, stream>>>(dstA, deg, E);
    k_dinv<<<ngrid, THREADS, 0, stream>>>(deg, dinv, N);
    k_chunk_sums<<<nChunks, THREADS, 0, stream>>>(deg, chunkSum, N);
    k_scan_offsets<<<1, 64, 0, stream>>>(chunkSum, chunkOff, nChunks, rowptr, N);
    k_scan_write<<<nChunks, THREADS, 0, stream>>>(deg, chunkOff, rowptr, N);
    k_cursor<<<ngrid, THREADS, 0, stream>>>(rowptr, cursor, N);
    k_fill<<<egrid, THREADS, 0, stream>>>(srcA, dstA, dinv, cursor, csr_src, csr_norm, E);
    k_w2<<<64, THREADS, 0, stream>>>(W, Wres, b, bres, Bt, cvec);

    const long long n4 = (long long)N * 32;
    const int tgrid = imin((int)((n4 + THREADS - 1) / THREADS), 2048);
    k_tanh0<<<tgrid, THREADS, 0, stream>>>(x, Xh, n4);

    for (int l = 0; l < 4; ++l) {
        k_agg<<<(N + 3) / 4, THREADS, 0, stream>>>(Xh, rowptr, csr_src, csr_norm, dinv, Ph, N);
        k_gemm_mfma<<<(N + 127) / 128, THREADS, 0, stream>>>(Ph, Xh, Bt, cvec, X, Xh, N,
                                                             (l == 3) ? 1 : 0);
    }
}

// Round 3
// 773.317 us; speedup vs baseline: 1.6833x; 1.0908x over previous
//
#include <hip/hip_runtime.h>
#include <hip/hip_bf16.h>
#include <stdint.h>

#define THREADS 256
typedef unsigned short u16;
typedef unsigned int u32;
using frag_ab = __attribute__((ext_vector_type(8))) short;   // 8 bf16 (4 VGPR)
using f32x4  = __attribute__((ext_vector_type(4))) float;    // 4 fp32 acc

static inline int imin(int a, int b) { return a < b ? a : b; }

static __device__ inline u16 f2b(float f) {               // f32 -> bf16 RNE
    u32 u = __builtin_bit_cast(u32, f);
    return (u16)((u + 0x7FFFu + ((u >> 16) & 1u)) >> 16);
}
static __device__ inline float b2f_lo(u32 v) { return __builtin_bit_cast(float, v << 16); }
static __device__ inline float b2f_hi(u32 v) { return __builtin_bit_cast(float, v & 0xFFFF0000u); }

// ---------------- edge dtype detection (int32 vs int64) ----------------
__global__ void k_detect(const int* __restrict__ raw, int* __restrict__ flag) {
    __shared__ int found;
    if (threadIdx.x == 0) found = 0;
    __syncthreads();
    if (raw[2 * threadIdx.x + 1] != 0) atomicOr(&found, 1);
    __syncthreads();
    if (threadIdx.x == 0) *flag = found ? 0 : 1;  // 1 => int64
}

// ---------------- edges -> src/dst arrays + degree histogram (fused) ----------------
__global__ void k_cvt_hist(const int* __restrict__ raw, int* __restrict__ src,
                           int* __restrict__ dst, int* __restrict__ deg, int E,
                           const int* __restrict__ flag) {
    const bool is64 = (*flag != 0);
    int i = blockIdx.x * blockDim.x + threadIdx.x;
    const int stride = gridDim.x * blockDim.x;
    for (; i < E; i += stride) {
        int s, d;
        if (is64) { s = raw[2 * i]; d = raw[2 * E + 2 * i]; }
        else      { s = raw[i];     d = raw[E + i]; }
        src[i] = s; dst[i] = d;
        atomicAdd(&deg[d], 1);
    }
}

__global__ void k_dinv(const int* __restrict__ deg, float* __restrict__ dinv, int N) {
    int i = blockIdx.x * blockDim.x + threadIdx.x;
    const int stride = gridDim.x * blockDim.x;
    for (; i < N; i += stride) dinv[i] = rsqrtf((float)deg[i] + 1.0f);
}

// ---------------- exclusive scan of deg -> rowptr ----------------
__global__ void k_chunk_sums(const int* __restrict__ deg, int* __restrict__ chunkSum, int N) {
    __shared__ int sm[THREADS];
    const int base = blockIdx.x * 2048 + threadIdx.x * 8;
    int s = 0;
#pragma unroll
    for (int i = 0; i < 8; ++i) { int idx = base + i; if (idx < N) s += deg[idx]; }
    sm[threadIdx.x] = s;
    __syncthreads();
    for (int off = THREADS / 2; off > 0; off >>= 1) {
        if (threadIdx.x < off) sm[threadIdx.x] += sm[threadIdx.x + off];
        __syncthreads();
    }
    if (threadIdx.x == 0) chunkSum[blockIdx.x] = sm[0];
}

__global__ void k_scan_offsets(const int* __restrict__ chunkSum, int* __restrict__ chunkOff,
                               int nChunks, int* __restrict__ rowptr, int N) {
    if (blockIdx.x == 0 && threadIdx.x == 0) {
        int run = 0;
        for (int i = 0; i < nChunks; ++i) { chunkOff[i] = run; run += chunkSum[i]; }
        rowptr[N] = run;
    }
}

__global__ void k_scan_write(const int* __restrict__ deg, const int* __restrict__ chunkOff,
                             int* __restrict__ rowptr, int N) {
    __shared__ int sm[THREADS];
    const int tid = threadIdx.x;
    const int base = blockIdx.x * 2048 + tid * 8;
    int v[8]; int s = 0;
#pragma unroll
    for (int i = 0; i < 8; ++i) { int idx = base + i; v[i] = (idx < N) ? deg[idx] : 0; s += v[i]; }
    const int mysum = s;
    sm[tid] = s;
    __syncthreads();
    for (int off = 1; off < THREADS; off <<= 1) {
        int t = (tid >= off) ? sm[tid - off] : 0;
        __syncthreads();
        sm[tid] += t;
        __syncthreads();
    }
    int run = chunkOff[blockIdx.x] + sm[tid] - mysum;
#pragma unroll
    for (int i = 0; i < 8; ++i) {
        int idx = base + i;
        if (idx < N) { rowptr[idx] = run; run += v[i]; }
    }
}

// ---------------- CSR fill (src index only — 4B scatter per edge) ----------------
__global__ void k_cursor(const int* __restrict__ rowptr, int* __restrict__ cursor, int N) {
    int i = blockIdx.x * blockDim.x + threadIdx.x;
    const int stride = gridDim.x * blockDim.x;
    for (; i < N; i += stride) cursor[i] = rowptr[i];
}

__global__ void k_fill(const int* __restrict__ src, const int* __restrict__ dst,
                       int* __restrict__ cursor, int* __restrict__ csr_src, int E) {
    int i = blockIdx.x * blockDim.x + threadIdx.x;
    const int stride = gridDim.x * blockDim.x;
    for (; i < E; i += stride) {
        const int s = src[i], d = dst[i];
        const int p = atomicAdd(&cursor[d], 1);
        csr_src[p] = s;
    }
}

// ---- Bt[n][k] (128 x 256 bf16, col-major concat [W ; -(W@Wres)]) + cvec = b-bres ----
__global__ void k_w2(const float* __restrict__ W, const float* __restrict__ Wres,
                     const float* __restrict__ b, const float* __restrict__ bres,
                     u16* __restrict__ Bt, float* __restrict__ cvec) {
    const int gid = blockIdx.x * blockDim.x + threadIdx.x;
    if (gid < 128 * 128) {
        const int i = gid >> 7, n = gid & 127;   // i = K row of W2, n = output col
        float s = 0.f;
#pragma unroll 8
        for (int k = 0; k < 128; ++k) s += W[i * 128 + k] * Wres[k * 128 + n];
        Bt[n * 256 + 128 + i] = f2b(-s);              // residual half: -(W@Wres)[i][n]
        Bt[n * 256 + i]       = f2b(W[i * 128 + n]);  // conv half: W[i][n]
    }
    if (gid < 128) cvec[gid] = b[gid] - bres[gid];
}

// ---------------- Xh0 = bf16(tanh(x)) ----------------
__global__ void k_tanh0(const float* __restrict__ x, u16* __restrict__ Xh, long long n4) {
    long long i = blockIdx.x * (long long)blockDim.x + threadIdx.x;
    const long long stride = gridDim.x * (long long)blockDim.x;
    for (; i < n4; i += stride) {
        float4 v = ((const float4*)x)[i];
        u32 lo = f2b(tanhf(v.x)) | ((u32)f2b(tanhf(v.y)) << 16);
        u32 hi = f2b(tanhf(v.z)) | ((u32)f2b(tanhf(v.w)) << 16);
        ((uint2*)Xh)[i] = make_uint2(lo, hi);
    }
}

// ------- Ph = bf16(dinv[d] * (Σ dinv[s]·Xh[s] + dinv[d]·Xh[d])) -------
// one wave per node, bf16x2 per lane, fp32 accum, 4-edge unroll for MLP
__global__ void k_agg(const u16* __restrict__ Xh, const int* __restrict__ rowptr,
                      const int* __restrict__ csr_src, const float* __restrict__ dinv,
                      u16* __restrict__ Ph, int N) {
    const int wid = threadIdx.x >> 6;
    const int lane = threadIdx.x & 63;
    const int node = blockIdx.x * 4 + wid;
    if (node >= N) return;
    const int j0 = lane * 2;
    const float dn = dinv[node];
    const u32 xv = *(const u32*)&Xh[(size_t)node * 128 + j0];
    float a0 = dn * b2f_lo(xv), a1 = dn * b2f_hi(xv);
    const int e0 = rowptr[node], e1 = rowptr[node + 1];
    int e = e0;
    for (; e + 3 < e1; e += 4) {
        const int s0 = csr_src[e], s1 = csr_src[e + 1];
        const int s2 = csr_src[e + 2], s3 = csr_src[e + 3];
        const float w0 = dinv[s0], w1 = dinv[s1], w2 = dinv[s2], w3 = dinv[s3];
        const u32 v0 = *(const u32*)&Xh[(size_t)s0 * 128 + j0];
        const u32 v1 = *(const u32*)&Xh[(size_t)s1 * 128 + j0];
        const u32 v2 = *(const u32*)&Xh[(size_t)s2 * 128 + j0];
        const u32 v3 = *(const u32*)&Xh[(size_t)s3 * 128 + j0];
        a0 = fmaf(w0, b2f_lo(v0), a0); a1 = fmaf(w0, b2f_hi(v0), a1);
        a0 = fmaf(w1, b2f_lo(v1), a0); a1 = fmaf(w1, b2f_hi(v1), a1);
        a0 = fmaf(w2, b2f_lo(v2), a0); a1 = fmaf(w2, b2f_hi(v2), a1);
        a0 = fmaf(w3, b2f_lo(v3), a0); a1 = fmaf(w3, b2f_hi(v3), a1);
    }
    for (; e < e1; ++e) {
        const int s0 = csr_src[e];
        const float w0 = dinv[s0];
        const u32 v0 = *(const u32*)&Xh[(size_t)s0 * 128 + j0];
        a0 = fmaf(w0, b2f_lo(v0), a0); a1 = fmaf(w0, b2f_hi(v0), a1);
    }
    a0 *= dn; a1 *= dn;
    *(u32*)&Ph[(size_t)node * 128 + j0] = (u32)f2b(a0) | ((u32)f2b(a1) << 16);
}

// -------- Xh = bf16(tanh([Ph|Xh] @ Bt^T + cvec)); optionally fp32 out (last layer) ----
// 256 thr = 4 waves; block tile 128 rows x 128 cols; wave tile 32x128.
__global__ __launch_bounds__(256)
void k_gemm_mfma(const u16* __restrict__ Ph, const u16* __restrict__ Xh,
                 const u16* __restrict__ Bt, const float* __restrict__ cvec,
                 float* __restrict__ Xout, u16* __restrict__ XhOut, int M, int writeF32) {
    const int wid = threadIdx.x >> 6;
    const int lane = threadIdx.x & 63;
    const int rowbase = blockIdx.x * 128 + wid * 32;
    const int rl = lane & 15;
    const int kg = (lane >> 4) * 8;

    f32x4 acc[2][8];
#pragma unroll
    for (int i = 0; i < 2; ++i)
#pragma unroll
        for (int j = 0; j < 8; ++j) acc[i][j] = (f32x4){0.f, 0.f, 0.f, 0.f};

    const int r0 = rowbase + rl;
    const size_t ar0 = (size_t)((r0      < M) ? r0      : M - 1);
    const size_t ar1 = (size_t)((r0 + 16 < M) ? r0 + 16 : M - 1);

#pragma unroll 1
    for (int ks = 0; ks < 8; ++ks) {
        const u16* Abase = (ks < 4) ? Ph : Xh;
        const int kk = (ks & 3) * 32 + kg;       // k within the 128-wide A half
        const frag_ab a0 = *(const frag_ab*)&Abase[ar0 * 128 + kk];
        const frag_ab a1 = *(const frag_ab*)&Abase[ar1 * 128 + kk];
        const int kb = ks * 32 + kg;             // k within the 256-wide Bt row
#pragma unroll
        for (int nf = 0; nf < 8; ++nf) {
            const frag_ab bv = *(const frag_ab*)&Bt[(size_t)(nf * 16 + rl) * 256 + kb];
            acc[0][nf] = __builtin_amdgcn_mfma_f32_16x16x32_bf16(a0, bv, acc[0][nf], 0, 0, 0);
            acc[1][nf] = __builtin_amdgcn_mfma_f32_16x16x32_bf16(a1, bv, acc[1][nf], 0, 0, 0);
        }
    }

    const int rq = (lane >> 4) * 4;
#pragma unroll
    for (int mf = 0; mf < 2; ++mf) {
#pragma unroll
        for (int nf = 0; nf < 8; ++nf) {
            const int c = nf * 16 + rl;
            const float cv = cvec[c];
#pragma unroll
            for (int reg = 0; reg < 4; ++reg) {
                const int r = rowbase + mf * 16 + rq + reg;
                if (r < M) {
                    const float v = tanhf(acc[mf][nf][reg] + cv);
                    XhOut[(size_t)r * 128 + c] = f2b(v);
                    if (writeF32) Xout[(size_t)r * 128 + c] = v;
                }
            }
        }
    }
}

extern "C" void kernel_launch(void* const* d_in, const int* in_sizes, int n_in,
                              void* d_out, int out_size, void* d_ws, size_t ws_size,
                              hipStream_t stream) {
    const float* x    = (const float*)d_in[0];
    const int*   ei   = (const int*)d_in[1];
    const float* W    = (const float*)d_in[2];
    const float* b    = (const float*)d_in[3];
    const float* Wres = (const float*)d_in[4];
    const float* bres = (const float*)d_in[5];
    const int N = in_sizes[0] / 128;
    const int E = in_sizes[1] / 2;
    float* X = (float*)d_out;

    uint8_t* base = (uint8_t*)d_ws;
    size_t off = 0;
    auto carve = [&](size_t bytes) -> void* {
        void* p = base + off;
        off += (bytes + 255) & ~(size_t)255;
        return p;
    };
    u16*   Xh       = (u16*)carve((size_t)N * 128 * sizeof(u16));
    u16*   Ph       = (u16*)carve((size_t)N * 128 * sizeof(u16));
    int*   srcA     = (int*)carve((size_t)E * sizeof(int));
    int*   dstA     = (int*)carve((size_t)E * sizeof(int));
    int*   csr_src  = (int*)carve((size_t)E * sizeof(int));
    int*   deg      = (int*)carve((size_t)N * sizeof(int));
    int*   rowptr   = (int*)carve(((size_t)N + 1) * sizeof(int));
    int*   cursor   = (int*)carve((size_t)N * sizeof(int));
    float* dinv     = (float*)carve((size_t)N * sizeof(float));
    u16*   Bt       = (u16*)carve(128 * 256 * sizeof(u16));
    float* cvec     = (float*)carve(128 * sizeof(float));
    int*   chunkSum = (int*)carve(4096);
    int*   chunkOff = (int*)carve(4096);
    int*   flag     = (int*)carve(256);

    hipMemsetAsync(deg, 0, (size_t)N * sizeof(int), stream);

    const int egrid = imin((E + THREADS - 1) / THREADS, 2048);
    const int ngrid = imin((N + THREADS - 1) / THREADS, 2048);
    const int nChunks = (N + 2047) / 2048;

    k_detect<<<1, 256, 0, stream>>>(ei, flag);
    k_cvt_hist<<<egrid, THREADS, 0, stream>>>(ei, srcA, dstA, deg, E, flag);
    k_dinv<<<ngrid, THREADS, 0, stream>>>(deg, dinv, N);
    k_chunk_sums<<<nChunks, THREADS, 0, stream>>>(deg, chunkSum, N);
    k_scan_offsets<<<1, 64, 0, stream>>>(chunkSum, chunkOff, nChunks, rowptr, N);
    k_scan_write<<<nChunks, THREADS, 0, stream>>>(deg, chunkOff, rowptr, N);
    k_cursor<<<ngrid, THREADS, 0, stream>>>(rowptr, cursor, N);
    k_fill<<<egrid, THREADS, 0, stream>>>(srcA, dstA, cursor, csr_src, E);
    k_w2<<<64, THREADS, 0, stream>>>(W, Wres, b, bres, Bt, cvec);

    const long long n4 = (long long)N * 32;
    const int tgrid = imin((int)((n4 + THREADS - 1) / THREADS), 2048);
    k_tanh0<<<tgrid, THREADS, 0, stream>>>(x, Xh, n4);

    for (int l = 0; l < 4; ++l) {
        k_agg<<<(N + 3) / 4, THREADS, 0, stream>>>(Xh, rowptr, csr_src, dinv, Ph, N);
        k_gemm_mfma<<<(N + 127) / 128, THREADS, 0, stream>>>(Ph, Xh, Bt, cvec, X, Xh, N,
                                                             (l == 3) ? 1 : 0);
    }
}

// Round 5
// 587.205 us; speedup vs baseline: 2.2168x; 1.3169x over previous
//
#include <hip/hip_runtime.h>
#include <hip/hip_bf16.h>
#include <stdint.h>

#define THREADS 256
#define WB 256            // nodes per bucket
#define MAXNB 512         // max buckets (N <= 131072)
#define NBLK_A 512        // blocks in bucketing phase

typedef unsigned short u16;
typedef unsigned int u32;
using frag_ab = __attribute__((ext_vector_type(8))) short;   // 8 bf16 (4 VGPR)
using f32x4  = __attribute__((ext_vector_type(4))) float;    // 4 fp32 acc

static __host__ __device__ inline int imin(int a, int b) { return a < b ? a : b; }

static __device__ inline u16 f2b(float f) {               // f32 -> bf16 RNE
    u32 u = __builtin_bit_cast(u32, f);
    return (u16)((u + 0x7FFFu + ((u >> 16) & 1u)) >> 16);
}
static __device__ inline float b2f_lo(u32 v) { return __builtin_bit_cast(float, v << 16); }
static __device__ inline float b2f_hi(u32 v) { return __builtin_bit_cast(float, v & 0xFFFF0000u); }

static __device__ inline void fma8(float* a, float w, uint4 v) {
    a[0] = fmaf(w, b2f_lo(v.x), a[0]); a[1] = fmaf(w, b2f_hi(v.x), a[1]);
    a[2] = fmaf(w, b2f_lo(v.y), a[2]); a[3] = fmaf(w, b2f_hi(v.y), a[3]);
    a[4] = fmaf(w, b2f_lo(v.z), a[4]); a[5] = fmaf(w, b2f_hi(v.z), a[5]);
    a[6] = fmaf(w, b2f_lo(v.w), a[6]); a[7] = fmaf(w, b2f_hi(v.w), a[7]);
}

// ---------------- edge dtype detection (int32 vs int64) ----------------
__global__ void k_detect(const int* __restrict__ raw, int* __restrict__ flag) {
    __shared__ int found;
    if (threadIdx.x == 0) found = 0;
    __syncthreads();
    if (raw[2 * threadIdx.x + 1] != 0) atomicOr(&found, 1);
    __syncthreads();
    if (threadIdx.x == 0) *flag = found ? 0 : 1;  // 1 => int64
}

// ---------------- A1: per-block bucket histogram (LDS atomics only) ----------------
__global__ __launch_bounds__(256)
void k_bucket_count(const int* __restrict__ raw, int E, int EPB, int NB,
                    const int* __restrict__ flag, int* __restrict__ counts) {
    __shared__ int cnt[MAXNB];
    const int t = threadIdx.x, blk = blockIdx.x;
    for (int i = t; i < NB; i += THREADS) cnt[i] = 0;
    __syncthreads();
    const bool is64 = (*flag != 0);
    const int e0 = blk * EPB, e1 = imin(E, e0 + EPB);
    for (int e = e0 + t; e < e1; e += THREADS) {
        const int d = is64 ? raw[2 * E + 2 * e] : raw[E + e];
        atomicAdd(&cnt[d >> 8], 1);   // WB = 256
    }
    __syncthreads();
    for (int i = t; i < NB; i += THREADS) counts[i * NBLK_A + blk] = cnt[i];
}

// ---------------- chunked exclusive scan over counts[L] (in-place) ----------------
__global__ void k_chunk_sums(const int* __restrict__ a, int* __restrict__ chunkSum, int L) {
    __shared__ int sm[THREADS];
    const int base = blockIdx.x * 2048 + threadIdx.x * 8;
    int s = 0;
#pragma unroll
    for (int i = 0; i < 8; ++i) { int idx = base + i; if (idx < L) s += a[idx]; }
    sm[threadIdx.x] = s;
    __syncthreads();
    for (int off = THREADS / 2; off > 0; off >>= 1) {
        if (threadIdx.x < off) sm[threadIdx.x] += sm[threadIdx.x + off];
        __syncthreads();
    }
    if (threadIdx.x == 0) chunkSum[blockIdx.x] = sm[0];
}

__global__ void k_scan_offsets(const int* __restrict__ chunkSum, int* __restrict__ chunkOff,
                               int nChunks) {
    if (blockIdx.x == 0 && threadIdx.x == 0) {
        int run = 0;
        for (int i = 0; i < nChunks; ++i) { chunkOff[i] = run; run += chunkSum[i]; }
    }
}

__global__ void k_scan_write(int* __restrict__ a, const int* __restrict__ chunkOff, int L) {
    __shared__ int sm[THREADS];
    const int tid = threadIdx.x;
    const int base = blockIdx.x * 2048 + tid * 8;
    int v[8]; int s = 0;
#pragma unroll
    for (int i = 0; i < 8; ++i) { int idx = base + i; v[i] = (idx < L) ? a[idx] : 0; s += v[i]; }
    const int mysum = s;
    sm[tid] = s;
    __syncthreads();
    for (int off = 1; off < THREADS; off <<= 1) {
        int t = (tid >= off) ? sm[tid - off] : 0;
        __syncthreads();
        sm[tid] += t;
        __syncthreads();
    }
    int run = chunkOff[blockIdx.x] + sm[tid] - mysum;  // exclusive prefix
#pragma unroll
    for (int i = 0; i < 8; ++i) {
        int idx = base + i;
        if (idx < L) { a[idx] = run; run += v[i]; }
    }
}

// ---------------- A3: scatter (src,dst) pairs into bucket regions ----------------
__global__ __launch_bounds__(256)
void k_bucket_scatter(const int* __restrict__ raw, int E, int EPB, int NB,
                      const int* __restrict__ flag, const int* __restrict__ offs,
                      uint2* __restrict__ pairs) {
    __shared__ int cur[MAXNB];
    const int t = threadIdx.x, blk = blockIdx.x;
    for (int i = t; i < NB; i += THREADS) cur[i] = offs[i * NBLK_A + blk];
    __syncthreads();
    const bool is64 = (*flag != 0);
    const int e0 = blk * EPB, e1 = imin(E, e0 + EPB);
    for (int e = e0 + t; e < e1; e += THREADS) {
        int s, d;
        if (is64) { s = raw[2 * e]; d = raw[2 * E + 2 * e]; }
        else      { s = raw[e];     d = raw[E + e]; }
        const int p = atomicAdd(&cur[d >> 8], 1);
        pairs[p] = make_uint2((u32)s, (u32)d);
    }
}

// ---------------- B: per-bucket CSR build (deg/dinv/rowptr/csr_src) ----------------
__global__ __launch_bounds__(256)
void k_build(const uint2* __restrict__ pairs, const int* __restrict__ offs,
             int* __restrict__ rowptr, int* __restrict__ csr_src,
             float* __restrict__ dinv, int N, int NB, int E) {
    __shared__ int deg[WB];
    __shared__ int ptr[WB];
    __shared__ int cur[WB];
    const int k = blockIdx.x, t = threadIdx.x;
    const int base = offs[k * NBLK_A];
    const int end  = (k + 1 < NB) ? offs[(k + 1) * NBLK_A] : E;
    const int n0 = k * WB;
    deg[t] = 0;
    __syncthreads();
    for (int e = base + t; e < end; e += THREADS)
        atomicAdd(&deg[(int)pairs[e].y - n0], 1);
    __syncthreads();
    const int dv = deg[t];
    if (n0 + t < N) dinv[n0 + t] = rsqrtf((float)dv + 1.0f);
    ptr[t] = dv;
    __syncthreads();
    for (int off = 1; off < THREADS; off <<= 1) {
        int v = (t >= off) ? ptr[t - off] : 0;
        __syncthreads();
        ptr[t] += v;
        __syncthreads();
    }
    const int excl = ptr[t] - dv;
    if (n0 + t < N) rowptr[n0 + t] = base + excl;
    if (k == NB - 1 && t == 0) rowptr[N] = E;
    cur[t] = excl;
    __syncthreads();
    for (int e = base + t; e < end; e += THREADS) {
        const uint2 pr = pairs[e];
        const int p = atomicAdd(&cur[(int)pr.y - n0], 1);
        csr_src[base + p] = (int)pr.x;
    }
}

// ---- Bt[n][k] (128 x 256 bf16, col-major concat [W ; -(W@Wres)]) + cvec = b-bres ----
__global__ void k_w2(const float* __restrict__ W, const float* __restrict__ Wres,
                     const float* __restrict__ b, const float* __restrict__ bres,
                     u16* __restrict__ Bt, float* __restrict__ cvec) {
    const int gid = blockIdx.x * blockDim.x + threadIdx.x;
    if (gid < 128 * 128) {
        const int i = gid >> 7, n = gid & 127;
        float s = 0.f;
#pragma unroll 8
        for (int k = 0; k < 128; ++k) s += W[i * 128 + k] * Wres[k * 128 + n];
        Bt[n * 256 + 128 + i] = f2b(-s);
        Bt[n * 256 + i]       = f2b(W[i * 128 + n]);
    }
    if (gid < 128) cvec[gid] = b[gid] - bres[gid];
}

// ---------------- Xh0 = bf16(tanh(x)) ----------------
__global__ void k_tanh0(const float* __restrict__ x, u16* __restrict__ Xh, long long n4) {
    long long i = blockIdx.x * (long long)blockDim.x + threadIdx.x;
    const long long stride = gridDim.x * (long long)blockDim.x;
    for (; i < n4; i += stride) {
        float4 v = ((const float4*)x)[i];
        u32 lo = f2b(tanhf(v.x)) | ((u32)f2b(tanhf(v.y)) << 16);
        u32 hi = f2b(tanhf(v.z)) | ((u32)f2b(tanhf(v.w)) << 16);
        ((uint2*)Xh)[i] = make_uint2(lo, hi);
    }
}

// ------- Ph = bf16(dinv[d]*(Σ dinv[s]·Xh[s] + dinv[d]·Xh[d])), quarter-wave gather -------
// wave per node; 16 lanes cover one row (uint4 = 8 bf16/lane); 4 rows per wave-load.
__global__ __launch_bounds__(256)
void k_agg(const u16* __restrict__ Xh, const int* __restrict__ rowptr,
           const int* __restrict__ csr_src, const float* __restrict__ dinv,
           u16* __restrict__ Ph, int N) {
    const int wid = threadIdx.x >> 6;
    const int lane = threadIdx.x & 63;
    const int node = blockIdx.x * 4 + wid;
    if (node >= N) return;
    const int q = lane >> 4;          // quarter 0..3
    const int c8 = (lane & 15) * 8;   // 8-col group
    const float dn = dinv[node];
    float acc[8] = {0.f, 0.f, 0.f, 0.f, 0.f, 0.f, 0.f, 0.f};
    const int e0 = rowptr[node], e1 = rowptr[node + 1];
    if (q == 0) {                     // self-loop term
        const uint4 v = *(const uint4*)&Xh[(size_t)node * 128 + c8];
        fma8(acc, dn, v);
    }
    int e = e0 + q;
    for (; e + 4 < e1; e += 8) {      // 2 edges per quarter per iter
        const int s0 = csr_src[e];
        const int s1 = csr_src[e + 4];
        const float w0 = dinv[s0], w1 = dinv[s1];
        const uint4 v0 = *(const uint4*)&Xh[(size_t)s0 * 128 + c8];
        const uint4 v1 = *(const uint4*)&Xh[(size_t)s1 * 128 + c8];
        fma8(acc, w0, v0);
        fma8(acc, w1, v1);
    }
    if (e < e1) {
        const int s0 = csr_src[e];
        const float w0 = dinv[s0];
        const uint4 v0 = *(const uint4*)&Xh[(size_t)s0 * 128 + c8];
        fma8(acc, w0, v0);
    }
#pragma unroll
    for (int j = 0; j < 8; ++j) acc[j] += __shfl_xor(acc[j], 16);
#pragma unroll
    for (int j = 0; j < 8; ++j) acc[j] += __shfl_xor(acc[j], 32);
    if (q == 0) {
        u32 w0 = (u32)f2b(acc[0] * dn) | ((u32)f2b(acc[1] * dn) << 16);
        u32 w1 = (u32)f2b(acc[2] * dn) | ((u32)f2b(acc[3] * dn) << 16);
        u32 w2 = (u32)f2b(acc[4] * dn) | ((u32)f2b(acc[5] * dn) << 16);
        u32 w3 = (u32)f2b(acc[6] * dn) | ((u32)f2b(acc[7] * dn) << 16);
        *(uint4*)&Ph[(size_t)node * 128 + c8] = make_uint4(w0, w1, w2, w3);
    }
}

// -------- Xh = bf16(tanh([Ph|Xh] @ Bt^T + cvec)); fp32 out on last layer only ----
__global__ __launch_bounds__(256)
void k_gemm_mfma(const u16* __restrict__ Ph, const u16* __restrict__ Xh,
                 const u16* __restrict__ Bt, const float* __restrict__ cvec,
                 float* __restrict__ Xout, u16* __restrict__ XhOut, int M, int writeF32) {
    const int wid = threadIdx.x >> 6;
    const int lane = threadIdx.x & 63;
    const int rowbase = blockIdx.x * 128 + wid * 32;
    const int rl = lane & 15;
    const int kg = (lane >> 4) * 8;

    f32x4 acc[2][8];
#pragma unroll
    for (int i = 0; i < 2; ++i)
#pragma unroll
        for (int j = 0; j < 8; ++j) acc[i][j] = (f32x4){0.f, 0.f, 0.f, 0.f};

    const int r0 = rowbase + rl;
    const size_t ar0 = (size_t)((r0      < M) ? r0      : M - 1);
    const size_t ar1 = (size_t)((r0 + 16 < M) ? r0 + 16 : M - 1);

#pragma unroll 1
    for (int ks = 0; ks < 8; ++ks) {
        const u16* Abase = (ks < 4) ? Ph : Xh;
        const int kk = (ks & 3) * 32 + kg;
        const frag_ab a0 = *(const frag_ab*)&Abase[ar0 * 128 + kk];
        const frag_ab a1 = *(const frag_ab*)&Abase[ar1 * 128 + kk];
        const int kb = ks * 32 + kg;
#pragma unroll
        for (int nf = 0; nf < 8; ++nf) {
            const frag_ab bv = *(const frag_ab*)&Bt[(size_t)(nf * 16 + rl) * 256 + kb];
            acc[0][nf] = __builtin_amdgcn_mfma_f32_16x16x32_bf16(a0, bv, acc[0][nf], 0, 0, 0);
            acc[1][nf] = __builtin_amdgcn_mfma_f32_16x16x32_bf16(a1, bv, acc[1][nf], 0, 0, 0);
        }
    }

    const int rq = (lane >> 4) * 4;
#pragma unroll
    for (int mf = 0; mf < 2; ++mf) {
#pragma unroll
        for (int nf = 0; nf < 8; ++nf) {
            const int c = nf * 16 + rl;
            const float cv = cvec[c];
#pragma unroll
            for (int reg = 0; reg < 4; ++reg) {
                const int r = rowbase + mf * 16 + rq + reg;
                if (r < M) {
                    const float v = tanhf(acc[mf][nf][reg] + cv);
                    if (writeF32) Xout[(size_t)r * 128 + c] = v;
                    else          XhOut[(size_t)r * 128 + c] = f2b(v);
                }
            }
        }
    }
}

extern "C" void kernel_launch(void* const* d_in, const int* in_sizes, int n_in,
                              void* d_out, int out_size, void* d_ws, size_t ws_size,
                              hipStream_t stream) {
    const float* x    = (const float*)d_in[0];
    const int*   ei   = (const int*)d_in[1];
    const float* W    = (const float*)d_in[2];
    const float* b    = (const float*)d_in[3];
    const float* Wres = (const float*)d_in[4];
    const float* bres = (const float*)d_in[5];
    const int N = in_sizes[0] / 128;
    const int E = in_sizes[1] / 2;
    float* X = (float*)d_out;

    uint8_t* base = (uint8_t*)d_ws;
    size_t off = 0;
    auto carve = [&](size_t bytes) -> void* {
        void* p = base + off;
        off += (bytes + 255) & ~(size_t)255;
        return p;
    };
    const int NB = imin((N + WB - 1) / WB, MAXNB);
    const int L = NB * NBLK_A;

    u16*   Xh       = (u16*)carve((size_t)N * 128 * sizeof(u16));
    u16*   Ph       = (u16*)carve((size_t)N * 128 * sizeof(u16));
    uint2* pairs    = (uint2*)carve((size_t)E * sizeof(uint2));
    int*   csr_src  = (int*)carve((size_t)E * sizeof(int));
    int*   counts   = (int*)carve((size_t)L * sizeof(int));
    int*   rowptr   = (int*)carve(((size_t)N + 1) * sizeof(int));
    float* dinv     = (float*)carve((size_t)N * sizeof(float));
    u16*   Bt       = (u16*)carve(128 * 256 * sizeof(u16));
    float* cvec     = (float*)carve(128 * sizeof(float));
    int*   chunkSum = (int*)carve(4096);
    int*   chunkOff = (int*)carve(4096);
    int*   flag     = (int*)carve(256);

    const int EPB = (E + NBLK_A - 1) / NBLK_A;
    const int nChunks = (L + 2047) / 2048;

    k_detect<<<1, 256, 0, stream>>>(ei, flag);
    k_bucket_count<<<NBLK_A, THREADS, 0, stream>>>(ei, E, EPB, NB, flag, counts);
    k_chunk_sums<<<nChunks, THREADS, 0, stream>>>(counts, chunkSum, L);
    k_scan_offsets<<<1, 64, 0, stream>>>(chunkSum, chunkOff, nChunks);
    k_scan_write<<<nChunks, THREADS, 0, stream>>>(counts, chunkOff, L);
    k_bucket_scatter<<<NBLK_A, THREADS, 0, stream>>>(ei, E, EPB, NB, flag, counts, pairs);
    k_build<<<NB, THREADS, 0, stream>>>(pairs, counts, rowptr, csr_src, dinv, N, NB, E);
    k_w2<<<64, THREADS, 0, stream>>>(W, Wres, b, bres, Bt, cvec);

    const long long n4 = (long long)N * 32;
    const int tgrid = imin((int)((n4 + THREADS - 1) / THREADS), 2048);
    k_tanh0<<<tgrid, THREADS, 0, stream>>>(x, Xh, n4);

    for (int l = 0; l < 4; ++l) {
        k_agg<<<(N + 3) / 4, THREADS, 0, stream>>>(Xh, rowptr, csr_src, dinv, Ph, N);
        k_gemm_mfma<<<(N + 127) / 128, THREADS, 0, stream>>>(Ph, Xh, Bt, cvec, X, Xh, N,
                                                             (l == 3) ? 1 : 0);
    }
}

// Round 6
// 456.356 us; speedup vs baseline: 2.8524x; 1.2867x over previous
//
#include <hip/hip_runtime.h>
#include <hip/hip_bf16.h>
#include <stdint.h>

#define THREADS 256
#define WB 256            // nodes per bucket
#define MAXNB 512         // max buckets (N <= 131072)
#define NBLK_A 512        // blocks in bucketing phase

typedef unsigned short u16;
typedef unsigned int u32;
using frag_ab = __attribute__((ext_vector_type(8))) short;   // 8 bf16 (4 VGPR)
using f32x4  = __attribute__((ext_vector_type(4))) float;    // 4 fp32 acc

static __host__ __device__ inline int imin(int a, int b) { return a < b ? a : b; }

static __device__ inline u16 f2b(float f) {               // f32 -> bf16 RNE
    u32 u = __builtin_bit_cast(u32, f);
    return (u16)((u + 0x7FFFu + ((u >> 16) & 1u)) >> 16);
}
static __device__ inline float b2f_lo(u32 v) { return __builtin_bit_cast(float, v << 16); }
static __device__ inline float b2f_hi(u32 v) { return __builtin_bit_cast(float, v & 0xFFFF0000u); }

// exact formula tanh via HW exp2/rcp: rel err ~1e-6, correct at +-inf, NaN-free
static __device__ inline float tanh_fast(float x) {
    const float e = __builtin_amdgcn_exp2f(x * 2.8853900817779268f);  // 2*log2(e)
    return 1.0f - 2.0f * __builtin_amdgcn_rcpf(e + 1.0f);
}

static __device__ inline void fma8(float* a, float w, uint4 v) {
    a[0] = fmaf(w, b2f_lo(v.x), a[0]); a[1] = fmaf(w, b2f_hi(v.x), a[1]);
    a[2] = fmaf(w, b2f_lo(v.y), a[2]); a[3] = fmaf(w, b2f_hi(v.y), a[3]);
    a[4] = fmaf(w, b2f_lo(v.z), a[4]); a[5] = fmaf(w, b2f_hi(v.z), a[5]);
    a[6] = fmaf(w, b2f_lo(v.w), a[6]); a[7] = fmaf(w, b2f_hi(v.w), a[7]);
}

// ---------------- edge dtype detection (int32 vs int64) ----------------
__global__ void k_detect(const int* __restrict__ raw, int* __restrict__ flag) {
    __shared__ int found;
    if (threadIdx.x == 0) found = 0;
    __syncthreads();
    if (raw[2 * threadIdx.x + 1] != 0) atomicOr(&found, 1);
    __syncthreads();
    if (threadIdx.x == 0) *flag = found ? 0 : 1;  // 1 => int64
}

// ---------------- A1: per-block bucket histogram (LDS atomics only) ----------------
__global__ __launch_bounds__(256)
void k_bucket_count(const int* __restrict__ raw, int E, int EPB, int NB,
                    const int* __restrict__ flag, int* __restrict__ counts) {
    __shared__ int cnt[MAXNB];
    const int t = threadIdx.x, blk = blockIdx.x;
    for (int i = t; i < NB; i += THREADS) cnt[i] = 0;
    __syncthreads();
    const bool is64 = (*flag != 0);
    const int e0 = blk * EPB, e1 = imin(E, e0 + EPB);
    for (int e = e0 + t; e < e1; e += THREADS) {
        const int d = is64 ? raw[2 * E + 2 * e] : raw[E + e];
        atomicAdd(&cnt[d >> 8], 1);   // WB = 256
    }
    __syncthreads();
    for (int i = t; i < NB; i += THREADS) counts[i * NBLK_A + blk] = cnt[i];
}

// ---------------- chunked exclusive scan over counts[L] (in-place) ----------------
__global__ void k_chunk_sums(const int* __restrict__ a, int* __restrict__ chunkSum, int L) {
    __shared__ int sm[THREADS];
    const int base = blockIdx.x * 2048 + threadIdx.x * 8;
    int s = 0;
#pragma unroll
    for (int i = 0; i < 8; ++i) { int idx = base + i; if (idx < L) s += a[idx]; }
    sm[threadIdx.x] = s;
    __syncthreads();
    for (int off = THREADS / 2; off > 0; off >>= 1) {
        if (threadIdx.x < off) sm[threadIdx.x] += sm[threadIdx.x + off];
        __syncthreads();
    }
    if (threadIdx.x == 0) chunkSum[blockIdx.x] = sm[0];
}

__global__ void k_scan_offsets(const int* __restrict__ chunkSum, int* __restrict__ chunkOff,
                               int nChunks) {
    if (blockIdx.x == 0 && threadIdx.x == 0) {
        int run = 0;
        for (int i = 0; i < nChunks; ++i) { chunkOff[i] = run; run += chunkSum[i]; }
    }
}

__global__ void k_scan_write(int* __restrict__ a, const int* __restrict__ chunkOff, int L) {
    __shared__ int sm[THREADS];
    const int tid = threadIdx.x;
    const int base = blockIdx.x * 2048 + tid * 8;
    int v[8]; int s = 0;
#pragma unroll
    for (int i = 0; i < 8; ++i) { int idx = base + i; v[i] = (idx < L) ? a[idx] : 0; s += v[i]; }
    const int mysum = s;
    sm[tid] = s;
    __syncthreads();
    for (int off = 1; off < THREADS; off <<= 1) {
        int t = (tid >= off) ? sm[tid - off] : 0;
        __syncthreads();
        sm[tid] += t;
        __syncthreads();
    }
    int run = chunkOff[blockIdx.x] + sm[tid] - mysum;  // exclusive prefix
#pragma unroll
    for (int i = 0; i < 8; ++i) {
        int idx = base + i;
        if (idx < L) { a[idx] = run; run += v[i]; }
    }
}

// ---------------- A3: scatter (src,dst) pairs into bucket regions ----------------
__global__ __launch_bounds__(256)
void k_bucket_scatter(const int* __restrict__ raw, int E, int EPB, int NB,
                      const int* __restrict__ flag, const int* __restrict__ offs,
                      uint2* __restrict__ pairs) {
    __shared__ int cur[MAXNB];
    const int t = threadIdx.x, blk = blockIdx.x;
    for (int i = t; i < NB; i += THREADS) cur[i] = offs[i * NBLK_A + blk];
    __syncthreads();
    const bool is64 = (*flag != 0);
    const int e0 = blk * EPB, e1 = imin(E, e0 + EPB);
    for (int e = e0 + t; e < e1; e += THREADS) {
        int s, d;
        if (is64) { s = raw[2 * e]; d = raw[2 * E + 2 * e]; }
        else      { s = raw[e];     d = raw[E + e]; }
        const int p = atomicAdd(&cur[d >> 8], 1);
        pairs[p] = make_uint2((u32)s, (u32)d);
    }
}

// ---------------- B: per-bucket CSR build (deg/dinv/rowptr/csr_src) ----------------
__global__ __launch_bounds__(256)
void k_build(const uint2* __restrict__ pairs, const int* __restrict__ offs,
             int* __restrict__ rowptr, int* __restrict__ csr_src,
             float* __restrict__ dinv, int N, int NB, int E) {
    __shared__ int deg[WB];
    __shared__ int ptr[WB];
    __shared__ int cur[WB];
    const int k = blockIdx.x, t = threadIdx.x;
    const int base = offs[k * NBLK_A];
    const int end  = (k + 1 < NB) ? offs[(k + 1) * NBLK_A] : E;
    const int n0 = k * WB;
    deg[t] = 0;
    __syncthreads();
    for (int e = base + t; e < end; e += THREADS)
        atomicAdd(&deg[(int)pairs[e].y - n0], 1);
    __syncthreads();
    const int dv = deg[t];
    if (n0 + t < N) dinv[n0 + t] = rsqrtf((float)dv + 1.0f);
    ptr[t] = dv;
    __syncthreads();
    for (int off = 1; off < THREADS; off <<= 1) {
        int v = (t >= off) ? ptr[t - off] : 0;
        __syncthreads();
        ptr[t] += v;
        __syncthreads();
    }
    const int excl = ptr[t] - dv;
    if (n0 + t < N) rowptr[n0 + t] = base + excl;
    if (k == NB - 1 && t == 0) rowptr[N] = E;
    cur[t] = excl;
    __syncthreads();
    for (int e = base + t; e < end; e += THREADS) {
        const uint2 pr = pairs[e];
        const int p = atomicAdd(&cur[(int)pr.y - n0], 1);
        csr_src[base + p] = (int)pr.x;
    }
}

// ---- Bt[n][k] (128 x 256 bf16, col-major concat [W ; -(W@Wres)]) + cvec = b-bres ----
__global__ void k_w2(const float* __restrict__ W, const float* __restrict__ Wres,
                     const float* __restrict__ b, const float* __restrict__ bres,
                     u16* __restrict__ Bt, float* __restrict__ cvec) {
    const int gid = blockIdx.x * blockDim.x + threadIdx.x;
    if (gid < 128 * 128) {
        const int i = gid >> 7, n = gid & 127;
        float s = 0.f;
#pragma unroll 8
        for (int k = 0; k < 128; ++k) s += W[i * 128 + k] * Wres[k * 128 + n];
        Bt[n * 256 + 128 + i] = f2b(-s);
        Bt[n * 256 + i]       = f2b(W[i * 128 + n]);
    }
    if (gid < 128) cvec[gid] = b[gid] - bres[gid];
}

// ---------------- Xh0 = bf16(tanh(x)) ----------------
__global__ void k_tanh0(const float* __restrict__ x, u16* __restrict__ Xh, long long n4) {
    long long i = blockIdx.x * (long long)blockDim.x + threadIdx.x;
    const long long stride = gridDim.x * (long long)blockDim.x;
    for (; i < n4; i += stride) {
        float4 v = ((const float4*)x)[i];
        u32 lo = f2b(tanh_fast(v.x)) | ((u32)f2b(tanh_fast(v.y)) << 16);
        u32 hi = f2b(tanh_fast(v.z)) | ((u32)f2b(tanh_fast(v.w)) << 16);
        ((uint2*)Xh)[i] = make_uint2(lo, hi);
    }
}

// ------- Ph = bf16(dinv[d]*(Σ dinv[s]·Xh[s] + dinv[d]·Xh[d])), quarter-wave gather -------
// wave per node; 16 lanes cover one row (uint4 = 8 bf16/lane); 4-deep edge unroll.
__global__ __launch_bounds__(256)
void k_agg(const u16* __restrict__ Xh, const int* __restrict__ rowptr,
           const int* __restrict__ csr_src, const float* __restrict__ dinv,
           u16* __restrict__ Ph, int N) {
    const int wid = threadIdx.x >> 6;
    const int lane = threadIdx.x & 63;
    const int node = blockIdx.x * 4 + wid;
    if (node >= N) return;
    const int q = lane >> 4;          // quarter 0..3
    const int c8 = (lane & 15) * 8;   // 8-col group
    const float dn = dinv[node];
    float acc[8] = {0.f, 0.f, 0.f, 0.f, 0.f, 0.f, 0.f, 0.f};
    const int e0 = rowptr[node], e1 = rowptr[node + 1];
    if (q == 0) {                     // self-loop term
        const uint4 v = *(const uint4*)&Xh[(size_t)node * 128 + c8];
        fma8(acc, dn, v);
    }
    int e = e0 + q;
    for (; e + 12 < e1; e += 16) {    // 4 edges per quarter per iter
        const int s0 = csr_src[e];
        const int s1 = csr_src[e + 4];
        const int s2 = csr_src[e + 8];
        const int s3 = csr_src[e + 12];
        const float w0 = dinv[s0], w1 = dinv[s1], w2 = dinv[s2], w3 = dinv[s3];
        const uint4 v0 = *(const uint4*)&Xh[(size_t)s0 * 128 + c8];
        const uint4 v1 = *(const uint4*)&Xh[(size_t)s1 * 128 + c8];
        const uint4 v2 = *(const uint4*)&Xh[(size_t)s2 * 128 + c8];
        const uint4 v3 = *(const uint4*)&Xh[(size_t)s3 * 128 + c8];
        fma8(acc, w0, v0);
        fma8(acc, w1, v1);
        fma8(acc, w2, v2);
        fma8(acc, w3, v3);
    }
    for (; e < e1; e += 4) {
        const int s0 = csr_src[e];
        const float w0 = dinv[s0];
        const uint4 v0 = *(const uint4*)&Xh[(size_t)s0 * 128 + c8];
        fma8(acc, w0, v0);
    }
#pragma unroll
    for (int j = 0; j < 8; ++j) acc[j] += __shfl_xor(acc[j], 16);
#pragma unroll
    for (int j = 0; j < 8; ++j) acc[j] += __shfl_xor(acc[j], 32);
    if (q == 0) {
        u32 w0 = (u32)f2b(acc[0] * dn) | ((u32)f2b(acc[1] * dn) << 16);
        u32 w1 = (u32)f2b(acc[2] * dn) | ((u32)f2b(acc[3] * dn) << 16);
        u32 w2 = (u32)f2b(acc[4] * dn) | ((u32)f2b(acc[5] * dn) << 16);
        u32 w3 = (u32)f2b(acc[6] * dn) | ((u32)f2b(acc[7] * dn) << 16);
        *(uint4*)&Ph[(size_t)node * 128 + c8] = make_uint4(w0, w1, w2, w3);
    }
}

// -------- Xh = bf16(tanh([Ph|Xh] @ Bt^T + cvec)); fp32 out on last layer only ----
// Bt staged in LDS (64 KB, XOR-swizzled vs 16-way bank conflict); all 16 A-frag
// loads hoisted upfront (compile-time indices); fully unrolled 128-MFMA body.
static __device__ inline int swz(int row, int byteInRow) {
    return byteInRow ^ ((row & 7) << 4);
}

__global__ __launch_bounds__(256)
void k_gemm_mfma(const u16* __restrict__ Ph, const u16* __restrict__ Xh,
                 const u16* __restrict__ Bt, const float* __restrict__ cvec,
                 float* __restrict__ Xout, u16* __restrict__ XhOut, int M, int writeF32) {
    __shared__ u16 Bs[128 * 256];     // 64 KB, swizzled layout
    const int tid = threadIdx.x;

    // stage Bt -> LDS (coalesced 16B chunks, swizzled store)
#pragma unroll
    for (int p = 0; p < 16; ++p) {
        const int c = p * 256 + tid;          // chunk 0..4095
        const int row = c >> 5, col16 = c & 31;
        const uint4 v = *(const uint4*)&Bt[row * 256 + col16 * 8];
        *(uint4*)&Bs[row * 256 + (swz(row, col16 * 16) >> 1)] = v;
    }

    const int wid = tid >> 6;
    const int lane = tid & 63;
    const int rowbase = blockIdx.x * 128 + wid * 32;
    const int rl = lane & 15;
    const int kg = (lane >> 4) * 8;

    const int r0 = rowbase + rl;
    const size_t ar0 = (size_t)((r0      < M) ? r0      : M - 1);
    const size_t ar1 = (size_t)((r0 + 16 < M) ? r0 + 16 : M - 1);

    // hoist all A-fragment loads (16 x global_load_dwordx4 in flight)
    frag_ab a0[8], a1[8];
#pragma unroll
    for (int ks = 0; ks < 4; ++ks) {
        const int kk = ks * 32 + kg;
        a0[ks]     = *(const frag_ab*)&Ph[ar0 * 128 + kk];
        a1[ks]     = *(const frag_ab*)&Ph[ar1 * 128 + kk];
        a0[ks + 4] = *(const frag_ab*)&Xh[ar0 * 128 + kk];
        a1[ks + 4] = *(const frag_ab*)&Xh[ar1 * 128 + kk];
    }

    f32x4 acc[2][8];
#pragma unroll
    for (int i = 0; i < 2; ++i)
#pragma unroll
        for (int j = 0; j < 8; ++j) acc[i][j] = (f32x4){0.f, 0.f, 0.f, 0.f};

    __syncthreads();

#pragma unroll
    for (int ks = 0; ks < 8; ++ks) {
        const int kbyte = ks * 64 + (kg * 2);   // byte offset within Bt row
#pragma unroll
        for (int nf = 0; nf < 8; ++nf) {
            const int r = nf * 16 + rl;
            const frag_ab bv = *(const frag_ab*)&Bs[r * 256 + (swz(r, kbyte) >> 1)];
            acc[0][nf] = __builtin_amdgcn_mfma_f32_16x16x32_bf16(a0[ks], bv, acc[0][nf], 0, 0, 0);
            acc[1][nf] = __builtin_amdgcn_mfma_f32_16x16x32_bf16(a1[ks], bv, acc[1][nf], 0, 0, 0);
        }
    }

    const int rq = (lane >> 4) * 4;
#pragma unroll
    for (int mf = 0; mf < 2; ++mf) {
#pragma unroll
        for (int nf = 0; nf < 8; ++nf) {
            const int c = nf * 16 + rl;
            const float cv = cvec[c];
#pragma unroll
            for (int reg = 0; reg < 4; ++reg) {
                const int r = rowbase + mf * 16 + rq + reg;
                if (r < M) {
                    const float v = tanh_fast(acc[mf][nf][reg] + cv);
                    if (writeF32) Xout[(size_t)r * 128 + c] = v;
                    else          XhOut[(size_t)r * 128 + c] = f2b(v);
                }
            }
        }
    }
}

extern "C" void kernel_launch(void* const* d_in, const int* in_sizes, int n_in,
                              void* d_out, int out_size, void* d_ws, size_t ws_size,
                              hipStream_t stream) {
    const float* x    = (const float*)d_in[0];
    const int*   ei   = (const int*)d_in[1];
    const float* W    = (const float*)d_in[2];
    const float* b    = (const float*)d_in[3];
    const float* Wres = (const float*)d_in[4];
    const float* bres = (const float*)d_in[5];
    const int N = in_sizes[0] / 128;
    const int E = in_sizes[1] / 2;
    float* X = (float*)d_out;

    uint8_t* base = (uint8_t*)d_ws;
    size_t off = 0;
    auto carve = [&](size_t bytes) -> void* {
        void* p = base + off;
        off += (bytes + 255) & ~(size_t)255;
        return p;
    };
    const int NB = imin((N + WB - 1) / WB, MAXNB);
    const int L = NB * NBLK_A;

    u16*   Xh       = (u16*)carve((size_t)N * 128 * sizeof(u16));
    u16*   Ph       = (u16*)carve((size_t)N * 128 * sizeof(u16));
    uint2* pairs    = (uint2*)carve((size_t)E * sizeof(uint2));
    int*   csr_src  = (int*)carve((size_t)E * sizeof(int));
    int*   counts   = (int*)carve((size_t)L * sizeof(int));
    int*   rowptr   = (int*)carve(((size_t)N + 1) * sizeof(int));
    float* dinv     = (float*)carve((size_t)N * sizeof(float));
    u16*   Bt       = (u16*)carve(128 * 256 * sizeof(u16));
    float* cvec     = (float*)carve(128 * sizeof(float));
    int*   chunkSum = (int*)carve(4096);
    int*   chunkOff = (int*)carve(4096);
    int*   flag     = (int*)carve(256);

    const int EPB = (E + NBLK_A - 1) / NBLK_A;
    const int nChunks = (L + 2047) / 2048;

    k_detect<<<1, 256, 0, stream>>>(ei, flag);
    k_bucket_count<<<NBLK_A, THREADS, 0, stream>>>(ei, E, EPB, NB, flag, counts);
    k_chunk_sums<<<nChunks, THREADS, 0, stream>>>(counts, chunkSum, L);
    k_scan_offsets<<<1, 64, 0, stream>>>(chunkSum, chunkOff, nChunks);
    k_scan_write<<<nChunks, THREADS, 0, stream>>>(counts, chunkOff, L);
    k_bucket_scatter<<<NBLK_A, THREADS, 0, stream>>>(ei, E, EPB, NB, flag, counts, pairs);
    k_build<<<NB, THREADS, 0, stream>>>(pairs, counts, rowptr, csr_src, dinv, N, NB, E);
    k_w2<<<64, THREADS, 0, stream>>>(W, Wres, b, bres, Bt, cvec);

    const long long n4 = (long long)N * 32;
    const int tgrid = imin((int)((n4 + THREADS - 1) / THREADS), 2048);
    k_tanh0<<<tgrid, THREADS, 0, stream>>>(x, Xh, n4);

    for (int l = 0; l < 4; ++l) {
        k_agg<<<(N + 3) / 4, THREADS, 0, stream>>>(Xh, rowptr, csr_src, dinv, Ph, N);
        k_gemm_mfma<<<(N + 127) / 128, THREADS, 0, stream>>>(Ph, Xh, Bt, cvec, X, Xh, N,
                                                             (l == 3) ? 1 : 0);
    }
}